// Round 1
// baseline (363.090 us; speedup 1.0000x reference)
//
#include <hip/hip_runtime.h>
#include <cstdint>

typedef unsigned short u16;
typedef uint32_t u32;

typedef __bf16 bf16x8 __attribute__((ext_vector_type(8)));
typedef float  f32x4  __attribute__((ext_vector_type(4)));
typedef u16    u16x4  __attribute__((ext_vector_type(4)));
typedef u16    u16x8  __attribute__((ext_vector_type(8)));

__device__ __forceinline__ u16 f2bf(float f) {
    u32 x = __float_as_uint(f);
    return (u16)((x + 0x7FFFu + ((x >> 16) & 1u)) >> 16);
}
__device__ __forceinline__ float lrelu(float x) { return fmaxf(x, 0.1f * x); }

// ---------------------------------------------------------------------------
// Prep: x -> xb bf16 [b][l][e]; conv_w -> wcb bf16 [c][tap*512+e];
//       W2/3/4 -> wsW bf16; hW[b][d] = h @ W1jh.T
// ---------------------------------------------------------------------------
__global__ __launch_bounds__(256) void k_prep(
    const float* __restrict__ x, const float* __restrict__ conv_w,
    const float* __restrict__ W2, const float* __restrict__ W3, const float* __restrict__ W4,
    const float* __restrict__ h, const float* __restrict__ W1,
    u16* __restrict__ xb, u16* __restrict__ wcb, u16* __restrict__ wsW,
    float* __restrict__ hW)
{
    int blk = blockIdx.x, tid = threadIdx.x;
    if (blk < 1280) {                       // xb: 1,310,720 elems, 4/thread
        int o = (blk * 256 + tid) * 4;
        int e = o & 511;
        int bl = o >> 9;
        int b = bl / 160, l = bl % 160;
        f32x4 v = *(const f32x4*)(x + ((size_t)(l * 16 + b)) * 512 + e);
        u16x4 ov;
        ov[0] = f2bf(v[0]); ov[1] = f2bf(v[1]); ov[2] = f2bf(v[2]); ov[3] = f2bf(v[3]);
        *(u16x4*)&xb[o] = ov;
    } else if (blk < 1664) {                // wcb: 393,216 elems
        int o = ((blk - 1280) * 256 + tid) * 4;
        int c = o / 1536, rem = o % 1536;
        int t = rem >> 9, e0 = rem & 511;
        u16x4 ov;
        #pragma unroll
        for (int q = 0; q < 4; q++)
            ov[q] = f2bf(conv_w[((size_t)c * 512 + e0 + q) * 3 + t]);
        *(u16x4*)&wcb[o] = ov;
    } else if (blk < 1712) {                // wsW: 49,152 elems
        int o = ((blk - 1664) * 256 + tid) * 4;
        int layer = o / 16384, rem = o % 16384;
        const float* W = (layer == 0) ? W2 : (layer == 1) ? W3 : W4;
        f32x4 v = *(const f32x4*)(W + rem);
        u16x4 ov;
        ov[0] = f2bf(v[0]); ov[1] = f2bf(v[1]); ov[2] = f2bf(v[2]); ov[3] = f2bf(v[3]);
        *(u16x4*)&wsW[o] = ov;
    } else {                                // hW: 2048 outputs
        int gid = (blk - 1712) * 256 + tid;
        int b = gid >> 7, d = gid & 127;
        const float* hr = h + (size_t)b * 512;
        const float* wr = W1 + (size_t)d * 1028 + 516;
        float acc = 0.f;
        for (int k = 0; k < 512; k += 4)
            acc += hr[k]*wr[k] + hr[k+1]*wr[k+1] + hr[k+2]*wr[k+2] + hr[k+3]*wr[k+3];
        hW[gid] = acc;
    }
}

// ---------------------------------------------------------------------------
// Conv1d (K=3, pad 1) as im2col GEMM, bf16 MFMA. M-tile = 32 l's, N-tile = 64 c's.
// Epilogue: +bias, lrelu, write y [b][l][c] fp32, atomic BN stats.
// ---------------------------------------------------------------------------
__global__ __launch_bounds__(256, 2) void k_conv(
    const u16* __restrict__ xb, const u16* __restrict__ wcb,
    const float* __restrict__ conv_b,
    float* __restrict__ ws_y, float* __restrict__ stats)
{
    __shared__ u16 xs[34 * 520];            // 34 rows (l0-1..l0+32) x 512 e, pad 8
    int tid = threadIdx.x, wg = blockIdx.x;
    int rowtile = wg >> 2, cg = wg & 3;
    int b = rowtile / 5, l0 = (rowtile % 5) * 32;

    for (int t = tid; t < 34 * 64; t += 256) {
        int s = t >> 6, ch = t & 63;
        int lg = l0 + s - 1;
        u16x8 v = {};
        if (lg >= 0 && lg < 160)
            v = *(const u16x8*)(xb + ((size_t)(b * 160 + lg)) * 512 + ch * 8);
        *(u16x8*)&xs[s * 520 + ch * 8] = v;
    }
    __syncthreads();

    int lane = tid & 63, w = tid >> 6;
    int row16 = lane & 15, quad = lane >> 4;
    int c_n = cg * 64 + w * 16 + row16;
    const u16* wrow = wcb + (size_t)c_n * 1536;

    f32x4 acc0 = {0,0,0,0}, acc1 = {0,0,0,0};
    for (int ks = 0; ks < 48; ks++) {
        int k = ks * 32 + quad * 8;
        int tap = k >> 9, e = k & 511;
        bf16x8 bfr = *(const bf16x8*)(wrow + k);
        bf16x8 a0 = *(const bf16x8*)&xs[(row16 + tap) * 520 + e];
        bf16x8 a1 = *(const bf16x8*)&xs[(16 + row16 + tap) * 520 + e];
        acc0 = __builtin_amdgcn_mfma_f32_16x16x32_bf16(a0, bfr, acc0, 0, 0, 0);
        acc1 = __builtin_amdgcn_mfma_f32_16x16x32_bf16(a1, bfr, acc1, 0, 0, 0);
    }

    float bias = conv_b[c_n];
    float sum = 0.f, sq = 0.f;
    #pragma unroll
    for (int mt = 0; mt < 2; mt++) {
        f32x4 a = mt ? acc1 : acc0;
        #pragma unroll
        for (int r = 0; r < 4; r++) {
            float v = lrelu(a[r] + bias);
            int lr = l0 + mt * 16 + quad * 4 + r;
            ws_y[((size_t)(b * 160 + lr)) * 256 + c_n] = v;
            sum += v; sq += v * v;
        }
    }
    sum += __shfl_xor(sum, 16); sum += __shfl_xor(sum, 32);
    sq  += __shfl_xor(sq, 16);  sq  += __shfl_xor(sq, 32);
    if (quad == 0) {
        atomicAdd(&stats[c_n], sum);
        atomicAdd(&stats[256 + c_n], sq);
    }
}

// ---------------------------------------------------------------------------
// BN + coords -> xf, then u = xf@W1i.T, v' = xf@W1jx.T + hW + b1 (fp32 VALU).
// Block = 16 (b,l) rows; thread computes 4 rows x 4 d'.
// ---------------------------------------------------------------------------
__global__ __launch_bounds__(256) void k_uv(
    const float* __restrict__ ws_y, const float* __restrict__ stats,
    const float* __restrict__ bn_g, const float* __restrict__ bn_b,
    const float* __restrict__ W1, const float* __restrict__ b1,
    const float* __restrict__ hW,
    float* __restrict__ uu, float* __restrict__ vv)
{
    __shared__ float a_s[256], c_s[256];
    __shared__ float xfs[16 * 260];
    int tid = threadIdx.x;
    int row0 = blockIdx.x * 16;
    int b = row0 / 160, l0 = row0 % 160;
    {
        int c = tid;
        float mu  = stats[c] * (1.0f / 2560.0f);
        float var = stats[256 + c] * (1.0f / 2560.0f) - mu * mu;
        float rs  = rsqrtf(var + 1e-5f) * bn_g[c];
        a_s[c] = rs;
        c_s[c] = bn_b[c] - mu * rs;
    }
    __syncthreads();
    float sLf = sqrtf(160.0f);
    for (int idx = tid; idx < 16 * 258; idx += 256) {
        int r = idx / 258, c = idx - r * 258;
        int l = l0 + r;
        float v;
        if (c < 256) {
            v = ws_y[((size_t)(b * 160 + l)) * 256 + c] * a_s[c] + c_s[c];
        } else {
            float fi = (float)l;
            if (c == 256) v = (fi / sLf - 2.0f) * 0.5f;
            else { float m = fi - floorf(fi / sLf) * sLf; v = (m - 2.0f) * 0.5f; }
        }
        xfs[r * 260 + c] = v;
    }
    __syncthreads();

    int rg = tid >> 6, dg = tid & 63;
    bool isv = dg >= 32;
    int dbase = (isv ? (dg - 32) : dg) * 4;
    const float* wbase = W1 + (size_t)dbase * 1028 + (isv ? 258 : 0);
    float acc[4][4] = {};
    for (int c = 0; c < 258; c++) {
        float x0 = xfs[(rg * 4 + 0) * 260 + c];
        float x1 = xfs[(rg * 4 + 1) * 260 + c];
        float x2 = xfs[(rg * 4 + 2) * 260 + c];
        float x3 = xfs[(rg * 4 + 3) * 260 + c];
        #pragma unroll
        for (int dd = 0; dd < 4; dd++) {
            float wv = wbase[(size_t)dd * 1028 + c];
            acc[0][dd] += x0 * wv; acc[1][dd] += x1 * wv;
            acc[2][dd] += x2 * wv; acc[3][dd] += x3 * wv;
        }
    }
    for (int rr = 0; rr < 4; rr++) {
        int l = l0 + rg * 4 + rr;
        #pragma unroll
        for (int dd = 0; dd < 4; dd++) {
            int d = dbase + dd;
            float v = acc[rr][dd];
            if (isv) v += hW[b * 128 + d] + b1[d];
            float* dst = isv ? vv : uu;
            dst[((size_t)(b * 160 + l)) * 128 + d] = v;
        }
    }
}

// ---------------------------------------------------------------------------
// Fused pairwise MLP: per WG one 8i x 16j = 128-pair tile.
// z in LDS bf16 [m][136]; 3 layers of 128x128 bf16 MFMA (weights from global);
// final sum over pairs -> atomic into s_glob[b][128].
// ---------------------------------------------------------------------------
__global__ __launch_bounds__(256, 2) void k_mlp(
    const float* __restrict__ vv, const float* __restrict__ uu,
    const u16* __restrict__ wsW,
    const float* __restrict__ b2, const float* __restrict__ b3,
    const float* __restrict__ b4,
    float* __restrict__ s_glob)
{
    __shared__ u16 zbuf[128 * 136];
    __shared__ float spart[128];
    int tid = threadIdx.x, blk = blockIdx.x;
    int b = blk / 200, r2 = blk % 200;
    int i0 = (r2 / 10) * 8, j0 = (r2 % 10) * 16;
    if (tid < 128) spart[tid] = 0.f;

    // build z0 = lrelu(v'_i + u_j), bf16 into LDS
    {
        int m = tid >> 1, kh = (tid & 1) * 64;
        int i = i0 + (m >> 4), j = j0 + (m & 15);
        const float* vr = vv + ((size_t)(b * 160 + i)) * 128 + kh;
        const float* ur = uu + ((size_t)(b * 160 + j)) * 128 + kh;
        for (int c = 0; c < 64; c += 8) {
            f32x4 a0 = *(const f32x4*)(vr + c);
            f32x4 b0 = *(const f32x4*)(ur + c);
            f32x4 a1 = *(const f32x4*)(vr + c + 4);
            f32x4 b1v = *(const f32x4*)(ur + c + 4);
            u16x8 o;
            o[0] = f2bf(lrelu(a0[0] + b0[0]));  o[1] = f2bf(lrelu(a0[1] + b0[1]));
            o[2] = f2bf(lrelu(a0[2] + b0[2]));  o[3] = f2bf(lrelu(a0[3] + b0[3]));
            o[4] = f2bf(lrelu(a1[0] + b1v[0])); o[5] = f2bf(lrelu(a1[1] + b1v[1]));
            o[6] = f2bf(lrelu(a1[2] + b1v[2])); o[7] = f2bf(lrelu(a1[3] + b1v[3]));
            *(u16x8*)&zbuf[m * 136 + kh + c] = o;
        }
    }
    __syncthreads();

    int lane = tid & 63, w = tid >> 6;
    int row16 = lane & 15, quad = lane >> 4;
    int mtb = (w & 1) * 4, ntb = (w >> 1) * 4;
    float ssum[4] = {0, 0, 0, 0};

    for (int layer = 0; layer < 3; layer++) {
        const u16* W = wsW + layer * 16384;
        const float* bp = (layer == 0) ? b2 : (layer == 1) ? b3 : b4;

        bf16x8 bfr[4][4];
        #pragma unroll
        for (int nt = 0; nt < 4; nt++)
            #pragma unroll
            for (int ks = 0; ks < 4; ks++)
                bfr[nt][ks] = *(const bf16x8*)(W + ((ntb + nt) * 16 + row16) * 128 + ks * 32 + quad * 8);

        f32x4 acc[4][4];
        #pragma unroll
        for (int mt = 0; mt < 4; mt++)
            #pragma unroll
            for (int nt = 0; nt < 4; nt++)
                acc[mt][nt] = (f32x4){0, 0, 0, 0};

        #pragma unroll
        for (int mt = 0; mt < 4; mt++) {
            bf16x8 af[4];
            #pragma unroll
            for (int ks = 0; ks < 4; ks++)
                af[ks] = *(const bf16x8*)&zbuf[((mtb + mt) * 16 + row16) * 136 + ks * 32 + quad * 8];
            #pragma unroll
            for (int nt = 0; nt < 4; nt++)
                #pragma unroll
                for (int ks = 0; ks < 4; ks++)
                    acc[mt][nt] = __builtin_amdgcn_mfma_f32_16x16x32_bf16(af[ks], bfr[nt][ks], acc[mt][nt], 0, 0, 0);
        }

        float bias_n[4];
        #pragma unroll
        for (int nt = 0; nt < 4; nt++)
            bias_n[nt] = bp[(ntb + nt) * 16 + row16];

        __syncthreads();   // all zbuf reads for this layer complete
        if (layer < 2) {
            #pragma unroll
            for (int mt = 0; mt < 4; mt++)
                #pragma unroll
                for (int nt = 0; nt < 4; nt++)
                    #pragma unroll
                    for (int r = 0; r < 4; r++) {
                        float v = lrelu(acc[mt][nt][r] + bias_n[nt]);
                        zbuf[((mtb + mt) * 16 + quad * 4 + r) * 136 + (ntb + nt) * 16 + row16] = f2bf(v);
                    }
            __syncthreads();
        } else {
            #pragma unroll
            for (int nt = 0; nt < 4; nt++) {
                float t = 0.f;
                #pragma unroll
                for (int mt = 0; mt < 4; mt++)
                    #pragma unroll
                    for (int r = 0; r < 4; r++)
                        t += lrelu(acc[mt][nt][r] + bias_n[nt]);
                ssum[nt] = t;
            }
        }
    }

    #pragma unroll
    for (int nt = 0; nt < 4; nt++) {
        float v = ssum[nt];
        v += __shfl_xor(v, 16);
        v += __shfl_xor(v, 32);
        if (quad == 0) atomicAdd(&spart[(ntb + nt) * 16 + row16], v);
    }
    __syncthreads();
    if (tid < 128) atomicAdd(&s_glob[b * 128 + tid], spart[tid]);
}

// ---------------------------------------------------------------------------
// Final: s -> lrelu(W5) -> lrelu(W6) -> out (fp32). One block per batch.
// ---------------------------------------------------------------------------
__global__ __launch_bounds__(128) void k_final(
    const float* __restrict__ s_glob,
    const float* __restrict__ W5, const float* __restrict__ b5,
    const float* __restrict__ W6, const float* __restrict__ b6,
    float* __restrict__ out)
{
    __shared__ float sh[128], t5[128];
    int b = blockIdx.x, t = threadIdx.x;
    sh[t] = s_glob[b * 128 + t];
    __syncthreads();
    float acc = b5[t];
    const float* wr = W5 + (size_t)t * 128;
    for (int k = 0; k < 128; k++) acc += sh[k] * wr[k];
    t5[t] = lrelu(acc);
    __syncthreads();
    for (int q = 0; q < 4; q++) {
        int o = q * 128 + t;
        const float* w6r = W6 + (size_t)o * 128;
        float a2 = b6[o];
        for (int k = 0; k < 128; k++) a2 += t5[k] * w6r[k];
        out[b * 512 + o] = lrelu(a2);
    }
}

// ---------------------------------------------------------------------------
extern "C" void kernel_launch(void* const* d_in, const int* in_sizes, int n_in,
                              void* d_out, int out_size, void* d_ws, size_t ws_size,
                              hipStream_t stream)
{
    const float* x      = (const float*)d_in[0];
    const float* h      = (const float*)d_in[1];
    const float* conv_w = (const float*)d_in[2];
    const float* conv_b = (const float*)d_in[3];
    const float* bn_g   = (const float*)d_in[4];
    const float* bn_b   = (const float*)d_in[5];
    const float* W1     = (const float*)d_in[6];
    const float* b1     = (const float*)d_in[7];
    const float* W2     = (const float*)d_in[8];
    const float* b2     = (const float*)d_in[9];
    const float* W3     = (const float*)d_in[10];
    const float* b3     = (const float*)d_in[11];
    const float* W4     = (const float*)d_in[12];
    const float* b4     = (const float*)d_in[13];
    const float* W5     = (const float*)d_in[14];
    const float* b5     = (const float*)d_in[15];
    const float* W6     = (const float*)d_in[16];
    const float* b6     = (const float*)d_in[17];

    char* ws = (char*)d_ws;
    float* s_glob = (float*)(ws + 0);          //  8 KB  (16x128)
    float* stats  = (float*)(ws + 8192);       //  2 KB  (sum|sq per channel)
    float* hW     = (float*)(ws + 10240);      //  8 KB  (16x128)
    float* ws_y   = (float*)(ws + 18432);      //  2.62 MB (b,l,c) fp32
    float* vv     = (float*)(ws + 2639872);    //  1.31 MB
    float* uu     = (float*)(ws + 3950592);    //  1.31 MB
    u16*   xb     = (u16*)  (ws + 5261312);    //  2.62 MB bf16
    u16*   wcb    = (u16*)  (ws + 7882752);    //  786 KB bf16
    u16*   wsW    = (u16*)  (ws + 8669184);    //   96 KB bf16  (end 8,767,488)

    hipMemsetAsync(ws, 0, 10240, stream);      // zero s_glob + stats
    k_prep <<<1720, 256, 0, stream>>>(x, conv_w, W2, W3, W4, h, W1, xb, wcb, wsW, hW);
    k_conv <<<320, 256, 0, stream>>>(xb, wcb, conv_b, ws_y, stats);
    k_uv   <<<160, 256, 0, stream>>>(ws_y, stats, bn_g, bn_b, W1, b1, hW, uu, vv);
    k_mlp  <<<3200, 256, 0, stream>>>(vv, uu, wsW, b2, b3, b4, s_glob);
    k_final<<<16, 128, 0, stream>>>(s_glob, W5, b5, W6, b6, (float*)d_out);
}

// Round 2
// 340.433 us; speedup vs baseline: 1.0666x; 1.0666x over previous
//
#include <hip/hip_runtime.h>
#include <cstdint>

typedef unsigned short u16;
typedef uint32_t u32;

typedef __bf16 bf16x8 __attribute__((ext_vector_type(8)));
typedef float  f32x4  __attribute__((ext_vector_type(4)));
typedef u16    u16x4  __attribute__((ext_vector_type(4)));
typedef u16    u16x8  __attribute__((ext_vector_type(8)));

__device__ __forceinline__ u16 f2bf(float f) {
    u32 x = __float_as_uint(f);
    return (u16)((x + 0x7FFFu + ((x >> 16) & 1u)) >> 16);
}
__device__ __forceinline__ float lrelu(float x) { return fmaxf(x, 0.1f * x); }

// ---------------------------------------------------------------------------
// Prep: x -> xb bf16 [b][l][e]; conv_w -> wcb bf16 [c][tap*512+e];
//       W2/3/4 -> wsW bf16; hW[b][d] = h @ W1jh.T
// ---------------------------------------------------------------------------
__global__ __launch_bounds__(256) void k_prep(
    const float* __restrict__ x, const float* __restrict__ conv_w,
    const float* __restrict__ W2, const float* __restrict__ W3, const float* __restrict__ W4,
    const float* __restrict__ h, const float* __restrict__ W1,
    u16* __restrict__ xb, u16* __restrict__ wcb, u16* __restrict__ wsW,
    float* __restrict__ hW)
{
    int blk = blockIdx.x, tid = threadIdx.x;
    if (blk < 1280) {                       // xb: 1,310,720 elems, 4/thread
        int o = (blk * 256 + tid) * 4;
        int e = o & 511;
        int bl = o >> 9;
        int b = bl / 160, l = bl % 160;
        f32x4 v = *(const f32x4*)(x + ((size_t)(l * 16 + b)) * 512 + e);
        u16x4 ov;
        ov[0] = f2bf(v[0]); ov[1] = f2bf(v[1]); ov[2] = f2bf(v[2]); ov[3] = f2bf(v[3]);
        *(u16x4*)&xb[o] = ov;
    } else if (blk < 1664) {                // wcb: 393,216 elems
        int o = ((blk - 1280) * 256 + tid) * 4;
        int c = o / 1536, rem = o % 1536;
        int t = rem >> 9, e0 = rem & 511;
        u16x4 ov;
        #pragma unroll
        for (int q = 0; q < 4; q++)
            ov[q] = f2bf(conv_w[((size_t)c * 512 + e0 + q) * 3 + t]);
        *(u16x4*)&wcb[o] = ov;
    } else if (blk < 1712) {                // wsW: 49,152 elems
        int o = ((blk - 1664) * 256 + tid) * 4;
        int layer = o / 16384, rem = o % 16384;
        const float* W = (layer == 0) ? W2 : (layer == 1) ? W3 : W4;
        f32x4 v = *(const f32x4*)(W + rem);
        u16x4 ov;
        ov[0] = f2bf(v[0]); ov[1] = f2bf(v[1]); ov[2] = f2bf(v[2]); ov[3] = f2bf(v[3]);
        *(u16x4*)&wsW[o] = ov;
    } else {                                // hW: 2048 outputs
        int gid = (blk - 1712) * 256 + tid;
        int b = gid >> 7, d = gid & 127;
        const float* hr = h + (size_t)b * 512;
        const float* wr = W1 + (size_t)d * 1028 + 516;
        float acc = 0.f;
        for (int k = 0; k < 512; k += 4)
            acc += hr[k]*wr[k] + hr[k+1]*wr[k+1] + hr[k+2]*wr[k+2] + hr[k+3]*wr[k+3];
        hW[gid] = acc;
    }
}

// ---------------------------------------------------------------------------
// Conv1d (K=3, pad 1) as im2col GEMM, bf16 MFMA. M-tile = 32 l's, N-tile = 64 c's.
// Unroll-4 weight prefetch so global loads batch instead of serializing.
// ---------------------------------------------------------------------------
__global__ __launch_bounds__(256, 2) void k_conv(
    const u16* __restrict__ xb, const u16* __restrict__ wcb,
    const float* __restrict__ conv_b,
    float* __restrict__ ws_y, float* __restrict__ stats)
{
    __shared__ u16 xs[34 * 520];            // 34 rows (l0-1..l0+32) x 512 e, pad 8
    int tid = threadIdx.x, wg = blockIdx.x;
    int rowtile = wg >> 2, cg = wg & 3;
    int b = rowtile / 5, l0 = (rowtile % 5) * 32;

    for (int t = tid; t < 34 * 64; t += 256) {
        int s = t >> 6, ch = t & 63;
        int lg = l0 + s - 1;
        u16x8 v = {};
        if (lg >= 0 && lg < 160)
            v = *(const u16x8*)(xb + ((size_t)(b * 160 + lg)) * 512 + ch * 8);
        *(u16x8*)&xs[s * 520 + ch * 8] = v;
    }
    __syncthreads();

    int lane = tid & 63, w = tid >> 6;
    int row16 = lane & 15, quad = lane >> 4;
    int c_n = cg * 64 + w * 16 + row16;
    const u16* wrow = wcb + (size_t)c_n * 1536;

    f32x4 acc0 = {0,0,0,0}, acc1 = {0,0,0,0};
    for (int ks4 = 0; ks4 < 48; ks4 += 4) {
        bf16x8 wf[4];
        #pragma unroll
        for (int q = 0; q < 4; q++)
            wf[q] = *(const bf16x8*)(wrow + (ks4 + q) * 32 + quad * 8);
        #pragma unroll
        for (int q = 0; q < 4; q++) {
            int k = (ks4 + q) * 32 + quad * 8;
            int tap = k >> 9, e = k & 511;
            bf16x8 a0 = *(const bf16x8*)&xs[(row16 + tap) * 520 + e];
            bf16x8 a1 = *(const bf16x8*)&xs[(16 + row16 + tap) * 520 + e];
            acc0 = __builtin_amdgcn_mfma_f32_16x16x32_bf16(a0, wf[q], acc0, 0, 0, 0);
            acc1 = __builtin_amdgcn_mfma_f32_16x16x32_bf16(a1, wf[q], acc1, 0, 0, 0);
        }
    }

    float bias = conv_b[c_n];
    float sum = 0.f, sq = 0.f;
    #pragma unroll
    for (int mt = 0; mt < 2; mt++) {
        f32x4 a = mt ? acc1 : acc0;
        #pragma unroll
        for (int r = 0; r < 4; r++) {
            float v = lrelu(a[r] + bias);
            int lr = l0 + mt * 16 + quad * 4 + r;
            ws_y[((size_t)(b * 160 + lr)) * 256 + c_n] = v;
            sum += v; sq += v * v;
        }
    }
    sum += __shfl_xor(sum, 16); sum += __shfl_xor(sum, 32);
    sq  += __shfl_xor(sq, 16);  sq  += __shfl_xor(sq, 32);
    if (quad == 0) {
        atomicAdd(&stats[c_n], sum);
        atomicAdd(&stats[256 + c_n], sq);
    }
}

// ---------------------------------------------------------------------------
// BN + coords -> xf (8 rows in LDS), then u/v projections.
// Each thread owns ONE output d' (u: tid<128, v: tid>=128) for all 8 rows.
// W1 row streamed via f32x4 into registers; x read from LDS broadcast.
// ---------------------------------------------------------------------------
__global__ __launch_bounds__(256) void k_uv(
    const float* __restrict__ ws_y, const float* __restrict__ stats,
    const float* __restrict__ bn_g, const float* __restrict__ bn_b,
    const float* __restrict__ W1, const float* __restrict__ b1,
    const float* __restrict__ hW,
    float* __restrict__ uu, float* __restrict__ vv)
{
    __shared__ float a_s[256], c_s[256];
    __shared__ float xfs[8 * 260];
    int tid = threadIdx.x;
    int row0 = blockIdx.x * 8;
    int b = row0 / 160, l0 = row0 % 160;
    {
        int c = tid;
        float mu  = stats[c] * (1.0f / 2560.0f);
        float var = stats[256 + c] * (1.0f / 2560.0f) - mu * mu;
        float rs  = rsqrtf(var + 1e-5f) * bn_g[c];
        a_s[c] = rs;
        c_s[c] = bn_b[c] - mu * rs;
    }
    __syncthreads();
    float sLf = sqrtf(160.0f);
    for (int idx = tid; idx < 8 * 258; idx += 256) {
        int r = idx / 258, c = idx - r * 258;
        int l = l0 + r;
        float v;
        if (c < 256) {
            v = ws_y[((size_t)(b * 160 + l)) * 256 + c] * a_s[c] + c_s[c];
        } else {
            float fi = (float)l;
            if (c == 256) v = (fi / sLf - 2.0f) * 0.5f;
            else { float m = fi - floorf(fi / sLf) * sLf; v = (m - 2.0f) * 0.5f; }
        }
        xfs[r * 260 + c] = v;
    }
    __syncthreads();

    bool isv = tid >= 128;
    int d = tid & 127;
    const float* wrow = W1 + (size_t)d * 1028 + (isv ? 258 : 0);

    float acc[8] = {0,0,0,0,0,0,0,0};
    for (int c0 = 0; c0 < 256; c0 += 32) {
        f32x4 wv[8];
        #pragma unroll
        for (int q = 0; q < 8; q++)
            wv[q] = *(const f32x4*)(wrow + c0 + q * 4);
        #pragma unroll
        for (int q = 0; q < 8; q++) {
            #pragma unroll
            for (int r = 0; r < 8; r++) {
                f32x4 xv = *(const f32x4*)&xfs[r * 260 + c0 + q * 4];
                acc[r] += wv[q][0]*xv[0] + wv[q][1]*xv[1] + wv[q][2]*xv[2] + wv[q][3]*xv[3];
            }
        }
    }
    float w256 = wrow[256], w257 = wrow[257];
    #pragma unroll
    for (int r = 0; r < 8; r++)
        acc[r] += xfs[r * 260 + 256] * w256 + xfs[r * 260 + 257] * w257;

    float vadd = isv ? (hW[b * 128 + d] + b1[d]) : 0.f;
    float* dst = isv ? vv : uu;
    #pragma unroll
    for (int r = 0; r < 8; r++)
        dst[((size_t)(b * 160 + l0 + r)) * 128 + d] = acc[r] + vadd;
}

// ---------------------------------------------------------------------------
// Fused pairwise MLP — barrier-free wave-slabs.
// Each wave owns 32 pairs (2 i x 16 j) in a wave-private LDS slab [32][136];
// 3 layers of 128x128 bf16 MFMA (weights from global/L1), no __syncthreads
// between layers. 2 barriers total (spart init / flush).
// ---------------------------------------------------------------------------
__global__ __launch_bounds__(256, 3) void k_mlp(
    const float* __restrict__ vv, const float* __restrict__ uu,
    const u16* __restrict__ wsW,
    const float* __restrict__ b2, const float* __restrict__ b3,
    const float* __restrict__ b4,
    float* __restrict__ s_glob)
{
    __shared__ u16 zall[4 * 32 * 136];
    __shared__ float spart[128];
    int tid = threadIdx.x, blk = blockIdx.x;
    int w = tid >> 6, lane = tid & 63;
    int s = blk * 4 + w;
    int b = s / 800, r2 = s % 800;
    int i0 = (r2 / 10) * 2, j0 = (r2 % 10) * 16;
    u16* zslab = zall + w * (32 * 136);

    if (tid < 128) spart[tid] = 0.f;
    __syncthreads();

    // build z0 = lrelu(v'_i + u_j) for this wave's 32 pairs
    {
        int m = lane >> 1, kh = (lane & 1) * 64;
        int i = i0 + (m >> 4), j = j0 + (m & 15);
        const float* vr = vv + ((size_t)(b * 160 + i)) * 128 + kh;
        const float* ur = uu + ((size_t)(b * 160 + j)) * 128 + kh;
        #pragma unroll
        for (int c = 0; c < 64; c += 8) {
            f32x4 a0 = *(const f32x4*)(vr + c);
            f32x4 b0 = *(const f32x4*)(ur + c);
            f32x4 a1 = *(const f32x4*)(vr + c + 4);
            f32x4 b1v = *(const f32x4*)(ur + c + 4);
            u16x8 o;
            o[0] = f2bf(lrelu(a0[0] + b0[0]));  o[1] = f2bf(lrelu(a0[1] + b0[1]));
            o[2] = f2bf(lrelu(a0[2] + b0[2]));  o[3] = f2bf(lrelu(a0[3] + b0[3]));
            o[4] = f2bf(lrelu(a1[0] + b1v[0])); o[5] = f2bf(lrelu(a1[1] + b1v[1]));
            o[6] = f2bf(lrelu(a1[2] + b1v[2])); o[7] = f2bf(lrelu(a1[3] + b1v[3]));
            *(u16x8*)&zslab[m * 136 + kh + c] = o;
        }
    }

    int row16 = lane & 15, quad = lane >> 4;
    f32x4 acc[2][8];
    float ssum[8];

    for (int layer = 0; layer < 3; layer++) {
        const u16* W = wsW + layer * 16384;
        const float* bp = (layer == 0) ? b2 : (layer == 1) ? b3 : b4;

        bf16x8 af[2][4];
        #pragma unroll
        for (int mt = 0; mt < 2; mt++)
            #pragma unroll
            for (int ks = 0; ks < 4; ks++)
                af[mt][ks] = *(const bf16x8*)&zslab[(mt * 16 + row16) * 136 + ks * 32 + quad * 8];

        float bias_n[8];
        #pragma unroll
        for (int nt = 0; nt < 8; nt++)
            bias_n[nt] = bp[nt * 16 + row16];

        #pragma unroll
        for (int nt = 0; nt < 8; nt++) {
            bf16x8 bfr[4];
            #pragma unroll
            for (int ks = 0; ks < 4; ks++)
                bfr[ks] = *(const bf16x8*)(W + (nt * 16 + row16) * 128 + ks * 32 + quad * 8);
            acc[0][nt] = (f32x4){0, 0, 0, 0};
            acc[1][nt] = (f32x4){0, 0, 0, 0};
            #pragma unroll
            for (int ks = 0; ks < 4; ks++) {
                acc[0][nt] = __builtin_amdgcn_mfma_f32_16x16x32_bf16(af[0][ks], bfr[ks], acc[0][nt], 0, 0, 0);
                acc[1][nt] = __builtin_amdgcn_mfma_f32_16x16x32_bf16(af[1][ks], bfr[ks], acc[1][nt], 0, 0, 0);
            }
        }

        if (layer < 2) {
            #pragma unroll
            for (int nt = 0; nt < 8; nt++)
                #pragma unroll
                for (int mt = 0; mt < 2; mt++)
                    #pragma unroll
                    for (int r = 0; r < 4; r++) {
                        float v = lrelu(acc[mt][nt][r] + bias_n[nt]);
                        zslab[(mt * 16 + quad * 4 + r) * 136 + nt * 16 + row16] = f2bf(v);
                    }
        } else {
            #pragma unroll
            for (int nt = 0; nt < 8; nt++) {
                float t = 0.f;
                #pragma unroll
                for (int mt = 0; mt < 2; mt++)
                    #pragma unroll
                    for (int r = 0; r < 4; r++)
                        t += lrelu(acc[mt][nt][r] + bias_n[nt]);
                ssum[nt] = t;
            }
        }
    }

    #pragma unroll
    for (int nt = 0; nt < 8; nt++) {
        float v = ssum[nt];
        v += __shfl_xor(v, 16);
        v += __shfl_xor(v, 32);
        if (quad == 0) atomicAdd(&spart[nt * 16 + row16], v);
    }
    __syncthreads();
    if (tid < 128) atomicAdd(&s_glob[b * 128 + tid], spart[tid]);
}

// ---------------------------------------------------------------------------
// Final: s -> lrelu(W5) -> lrelu(W6) -> out (fp32). One block per batch.
// ---------------------------------------------------------------------------
__global__ __launch_bounds__(128) void k_final(
    const float* __restrict__ s_glob,
    const float* __restrict__ W5, const float* __restrict__ b5,
    const float* __restrict__ W6, const float* __restrict__ b6,
    float* __restrict__ out)
{
    __shared__ float sh[128], t5[128];
    int b = blockIdx.x, t = threadIdx.x;
    sh[t] = s_glob[b * 128 + t];
    __syncthreads();
    float acc = b5[t];
    const float* wr = W5 + (size_t)t * 128;
    for (int k = 0; k < 128; k++) acc += sh[k] * wr[k];
    t5[t] = lrelu(acc);
    __syncthreads();
    for (int q = 0; q < 4; q++) {
        int o = q * 128 + t;
        const float* w6r = W6 + (size_t)o * 128;
        float a2 = b6[o];
        for (int k = 0; k < 128; k++) a2 += t5[k] * w6r[k];
        out[b * 512 + o] = lrelu(a2);
    }
}

// ---------------------------------------------------------------------------
extern "C" void kernel_launch(void* const* d_in, const int* in_sizes, int n_in,
                              void* d_out, int out_size, void* d_ws, size_t ws_size,
                              hipStream_t stream)
{
    const float* x      = (const float*)d_in[0];
    const float* h      = (const float*)d_in[1];
    const float* conv_w = (const float*)d_in[2];
    const float* conv_b = (const float*)d_in[3];
    const float* bn_g   = (const float*)d_in[4];
    const float* bn_b   = (const float*)d_in[5];
    const float* W1     = (const float*)d_in[6];
    const float* b1     = (const float*)d_in[7];
    const float* W2     = (const float*)d_in[8];
    const float* b2     = (const float*)d_in[9];
    const float* W3     = (const float*)d_in[10];
    const float* b3     = (const float*)d_in[11];
    const float* W4     = (const float*)d_in[12];
    const float* b4     = (const float*)d_in[13];
    const float* W5     = (const float*)d_in[14];
    const float* b5     = (const float*)d_in[15];
    const float* W6     = (const float*)d_in[16];
    const float* b6     = (const float*)d_in[17];

    char* ws = (char*)d_ws;
    float* s_glob = (float*)(ws + 0);          //  8 KB  (16x128)
    float* stats  = (float*)(ws + 8192);       //  2 KB  (sum|sq per channel)
    float* hW     = (float*)(ws + 10240);      //  8 KB  (16x128)
    float* ws_y   = (float*)(ws + 18432);      //  2.62 MB (b,l,c) fp32
    float* vv     = (float*)(ws + 2639872);    //  1.31 MB
    float* uu     = (float*)(ws + 3950592);    //  1.31 MB
    u16*   xb     = (u16*)  (ws + 5261312);    //  2.62 MB bf16
    u16*   wcb    = (u16*)  (ws + 7882752);    //  786 KB bf16
    u16*   wsW    = (u16*)  (ws + 8669184);    //   96 KB bf16  (end 8,767,488)

    hipMemsetAsync(ws, 0, 10240, stream);      // zero s_glob + stats
    k_prep <<<1720, 256, 0, stream>>>(x, conv_w, W2, W3, W4, h, W1, xb, wcb, wsW, hW);
    k_conv <<<320, 256, 0, stream>>>(xb, wcb, conv_b, ws_y, stats);
    k_uv   <<<320, 256, 0, stream>>>(ws_y, stats, bn_g, bn_b, W1, b1, hW, uu, vv);
    k_mlp  <<<3200, 256, 0, stream>>>(vv, uu, wsW, b2, b3, b4, s_glob);
    k_final<<<16, 128, 0, stream>>>(s_glob, W5, b5, W6, b6, (float*)d_out);
}

// Round 3
// 325.440 us; speedup vs baseline: 1.1157x; 1.0461x over previous
//
#include <hip/hip_runtime.h>
#include <cstdint>

typedef unsigned short u16;
typedef uint32_t u32;

typedef __bf16 bf16x8 __attribute__((ext_vector_type(8)));
typedef float  f32x4  __attribute__((ext_vector_type(4)));
typedef float  f32x16 __attribute__((ext_vector_type(16)));
typedef u16    u16x4  __attribute__((ext_vector_type(4)));
typedef u16    u16x8  __attribute__((ext_vector_type(8)));

__device__ __forceinline__ u16 f2bf(float f) {
    u32 x = __float_as_uint(f);
    return (u16)((x + 0x7FFFu + ((x >> 16) & 1u)) >> 16);
}
__device__ __forceinline__ float lrelu(float x) { return fmaxf(x, 0.1f * x); }

// pack two f32 -> one dword of two bf16 (round-to-nearest via +0x8000, then
// v_perm grabs the high halves): lo -> low16, hi -> high16. 3 VALU ops.
__device__ __forceinline__ u32 pack_rn(float lo, float hi) {
    u32 a = __float_as_uint(lo) + 0x8000u;
    u32 b = __float_as_uint(hi) + 0x8000u;
    return __builtin_amdgcn_perm(b, a, 0x07060302u);
}

// ---------------------------------------------------------------------------
// Prep: x -> xb bf16 [b][l][e]; conv_w -> wcb bf16 [c][tap*512+e];
//       W2/3/4+b2/3/4 -> wfrag (MFMA-A frag-blocked, bias as 9th K-tile);
//       hW[b][d] = h @ W1jh.T
// wfrag layout (u16): [layer][ks9][h][n][j8]  strides 18432/2048/1024/8/1
//   ks9<8: W[n][16*ks9 + 8*h + j];  ks9==8: (h==0&&j==0) ? bias[n] : 0
// ---------------------------------------------------------------------------
__global__ __launch_bounds__(256) void k_prep(
    const float* __restrict__ x, const float* __restrict__ conv_w,
    const float* __restrict__ W2, const float* __restrict__ W3, const float* __restrict__ W4,
    const float* __restrict__ b2, const float* __restrict__ b3, const float* __restrict__ b4,
    const float* __restrict__ h, const float* __restrict__ W1,
    u16* __restrict__ xb, u16* __restrict__ wcb, u16* __restrict__ wfrag,
    float* __restrict__ hW)
{
    int blk = blockIdx.x, tid = threadIdx.x;
    if (blk < 1280) {                       // xb: 1,310,720 elems, 4/thread
        int o = (blk * 256 + tid) * 4;
        int e = o & 511;
        int bl = o >> 9;
        int b = bl / 160, l = bl % 160;
        f32x4 v = *(const f32x4*)(x + ((size_t)(l * 16 + b)) * 512 + e);
        u16x4 ov;
        ov[0] = f2bf(v[0]); ov[1] = f2bf(v[1]); ov[2] = f2bf(v[2]); ov[3] = f2bf(v[3]);
        *(u16x4*)&xb[o] = ov;
    } else if (blk < 1664) {                // wcb: 393,216 elems
        int o = ((blk - 1280) * 256 + tid) * 4;
        int c = o / 1536, rem = o % 1536;
        int t = rem >> 9, e0 = rem & 511;
        u16x4 ov;
        #pragma unroll
        for (int q = 0; q < 4; q++)
            ov[q] = f2bf(conv_w[((size_t)c * 512 + e0 + q) * 3 + t]);
        *(u16x4*)&wcb[o] = ov;
    } else if (blk < 1718) {                // wfrag: 55,296 elems, 54 blocks
        int o = ((blk - 1664) * 256 + tid) * 4;
        int layer = o / 18432, rem = o % 18432;
        int ks9 = rem >> 11;                // /2048
        int rem2 = rem & 2047;
        int hh = rem2 >> 10;
        int rem3 = rem2 & 1023;
        int n = rem3 >> 3, j0 = rem3 & 7;   // j0 in {0,4}
        const float* W = (layer == 0) ? W2 : (layer == 1) ? W3 : W4;
        const float* bi = (layer == 0) ? b2 : (layer == 1) ? b3 : b4;
        u16x4 ov;
        if (ks9 < 8) {
            f32x4 v = *(const f32x4*)(W + (size_t)n * 128 + 16 * ks9 + 8 * hh + j0);
            ov[0] = f2bf(v[0]); ov[1] = f2bf(v[1]); ov[2] = f2bf(v[2]); ov[3] = f2bf(v[3]);
        } else {
            ov[0] = (hh == 0 && j0 == 0) ? f2bf(bi[n]) : (u16)0;
            ov[1] = 0; ov[2] = 0; ov[3] = 0;
        }
        *(u16x4*)&wfrag[o] = ov;
    } else {                                // hW: 2048 outputs, 8 blocks
        int gid = (blk - 1718) * 256 + tid;
        int b = gid >> 7, d = gid & 127;
        const float* hr = h + (size_t)b * 512;
        const float* wr = W1 + (size_t)d * 1028 + 516;
        float acc = 0.f;
        for (int k = 0; k < 512; k += 4)
            acc += hr[k]*wr[k] + hr[k+1]*wr[k+1] + hr[k+2]*wr[k+2] + hr[k+3]*wr[k+3];
        hW[gid] = acc;
    }
}

// ---------------------------------------------------------------------------
// Conv1d (K=3, pad 1) as im2col GEMM, bf16 MFMA (unchanged from round 2).
// ---------------------------------------------------------------------------
__global__ __launch_bounds__(256, 2) void k_conv(
    const u16* __restrict__ xb, const u16* __restrict__ wcb,
    const float* __restrict__ conv_b,
    float* __restrict__ ws_y, float* __restrict__ stats)
{
    __shared__ u16 xs[34 * 520];
    int tid = threadIdx.x, wg = blockIdx.x;
    int rowtile = wg >> 2, cg = wg & 3;
    int b = rowtile / 5, l0 = (rowtile % 5) * 32;

    for (int t = tid; t < 34 * 64; t += 256) {
        int s = t >> 6, ch = t & 63;
        int lg = l0 + s - 1;
        u16x8 v = {};
        if (lg >= 0 && lg < 160)
            v = *(const u16x8*)(xb + ((size_t)(b * 160 + lg)) * 512 + ch * 8);
        *(u16x8*)&xs[s * 520 + ch * 8] = v;
    }
    __syncthreads();

    int lane = tid & 63, w = tid >> 6;
    int row16 = lane & 15, quad = lane >> 4;
    int c_n = cg * 64 + w * 16 + row16;
    const u16* wrow = wcb + (size_t)c_n * 1536;

    f32x4 acc0 = {0,0,0,0}, acc1 = {0,0,0,0};
    for (int ks4 = 0; ks4 < 48; ks4 += 4) {
        bf16x8 wf[4];
        #pragma unroll
        for (int q = 0; q < 4; q++)
            wf[q] = *(const bf16x8*)(wrow + (ks4 + q) * 32 + quad * 8);
        #pragma unroll
        for (int q = 0; q < 4; q++) {
            int k = (ks4 + q) * 32 + quad * 8;
            int tap = k >> 9, e = k & 511;
            bf16x8 a0 = *(const bf16x8*)&xs[(row16 + tap) * 520 + e];
            bf16x8 a1 = *(const bf16x8*)&xs[(16 + row16 + tap) * 520 + e];
            acc0 = __builtin_amdgcn_mfma_f32_16x16x32_bf16(a0, wf[q], acc0, 0, 0, 0);
            acc1 = __builtin_amdgcn_mfma_f32_16x16x32_bf16(a1, wf[q], acc1, 0, 0, 0);
        }
    }

    float bias = conv_b[c_n];
    float sum = 0.f, sq = 0.f;
    #pragma unroll
    for (int mt = 0; mt < 2; mt++) {
        f32x4 a = mt ? acc1 : acc0;
        #pragma unroll
        for (int r = 0; r < 4; r++) {
            float v = lrelu(a[r] + bias);
            int lr = l0 + mt * 16 + quad * 4 + r;
            ws_y[((size_t)(b * 160 + lr)) * 256 + c_n] = v;
            sum += v; sq += v * v;
        }
    }
    sum += __shfl_xor(sum, 16); sum += __shfl_xor(sum, 32);
    sq  += __shfl_xor(sq, 16);  sq  += __shfl_xor(sq, 32);
    if (quad == 0) {
        atomicAdd(&stats[c_n], sum);
        atomicAdd(&stats[256 + c_n], sq);
    }
}

// ---------------------------------------------------------------------------
// BN + coords -> xf, u/v projections (unchanged from round 2).
// ---------------------------------------------------------------------------
__global__ __launch_bounds__(256) void k_uv(
    const float* __restrict__ ws_y, const float* __restrict__ stats,
    const float* __restrict__ bn_g, const float* __restrict__ bn_b,
    const float* __restrict__ W1, const float* __restrict__ b1,
    const float* __restrict__ hW,
    float* __restrict__ uu, float* __restrict__ vv)
{
    __shared__ float a_s[256], c_s[256];
    __shared__ float xfs[8 * 260];
    int tid = threadIdx.x;
    int row0 = blockIdx.x * 8;
    int b = row0 / 160, l0 = row0 % 160;
    {
        int c = tid;
        float mu  = stats[c] * (1.0f / 2560.0f);
        float var = stats[256 + c] * (1.0f / 2560.0f) - mu * mu;
        float rs  = rsqrtf(var + 1e-5f) * bn_g[c];
        a_s[c] = rs;
        c_s[c] = bn_b[c] - mu * rs;
    }
    __syncthreads();
    float sLf = sqrtf(160.0f);
    for (int idx = tid; idx < 8 * 258; idx += 256) {
        int r = idx / 258, c = idx - r * 258;
        int l = l0 + r;
        float v;
        if (c < 256) {
            v = ws_y[((size_t)(b * 160 + l)) * 256 + c] * a_s[c] + c_s[c];
        } else {
            float fi = (float)l;
            if (c == 256) v = (fi / sLf - 2.0f) * 0.5f;
            else { float m = fi - floorf(fi / sLf) * sLf; v = (m - 2.0f) * 0.5f; }
        }
        xfs[r * 260 + c] = v;
    }
    __syncthreads();

    bool isv = tid >= 128;
    int d = tid & 127;
    const float* wrow = W1 + (size_t)d * 1028 + (isv ? 258 : 0);

    float acc[8] = {0,0,0,0,0,0,0,0};
    for (int c0 = 0; c0 < 256; c0 += 32) {
        f32x4 wv[8];
        #pragma unroll
        for (int q = 0; q < 8; q++)
            wv[q] = *(const f32x4*)(wrow + c0 + q * 4);
        #pragma unroll
        for (int q = 0; q < 8; q++) {
            #pragma unroll
            for (int r = 0; r < 8; r++) {
                f32x4 xv = *(const f32x4*)&xfs[r * 260 + c0 + q * 4];
                acc[r] += wv[q][0]*xv[0] + wv[q][1]*xv[1] + wv[q][2]*xv[2] + wv[q][3]*xv[3];
            }
        }
    }
    float w256 = wrow[256], w257 = wrow[257];
    #pragma unroll
    for (int r = 0; r < 8; r++)
        acc[r] += xfs[r * 260 + 256] * w256 + xfs[r * 260 + 257] * w257;

    float vadd = isv ? (hW[b * 128 + d] + b1[d]) : 0.f;
    float* dst = isv ? vv : uu;
    #pragma unroll
    for (int r = 0; r < 8; r++)
        dst[((size_t)(b * 160 + l0 + r)) * 128 + d] = acc[r] + vadd;
}

// ---------------------------------------------------------------------------
// Fused pairwise MLP v3 — z stays in REGISTERS across all 3 layers.
// Computes z^T:  D[n][m] = W (as MFMA-A) x z^T (as MFMA-B), 32x32x16 bf16.
// C-layout -> next-layer B-layout done in-register (bpermute + v_perm).
// Weights staged one layer at a time in LDS (36.9KB), shared by the WG;
// bias folded in as a 9th K-tile. WG=256thr(4 waves), T=2 tiles/wave/phase.
// Grid: 512 WGs; WG wg: b = wg>>5, 25 tiles of 32 pairs (2i x 16j) each.
// ---------------------------------------------------------------------------
__global__ __launch_bounds__(256, 2) void k_mlp(
    const float* __restrict__ vv, const float* __restrict__ uu,
    const u16* __restrict__ wfrag,
    float* __restrict__ s_glob)
{
    __shared__ __align__(16) u16 Wlds[18432];   // [ks9][h][n][8]
    __shared__ float spart[128];
    int tid = threadIdx.x;
    int wave = tid >> 6, lane = tid & 63;
    int h = lane >> 5, lo = lane & 31;
    int b = blockIdx.x >> 5, sub = blockIdx.x & 31;

    if (tid < 128) spart[tid] = 0.f;

    u32 selv = h ? 0x07060302u : 0x05040100u;
    uint4 biasfrag;
    biasfrag.x = (h == 0) ? 0x00003F80u : 0u;   // bf16 1.0 at element j=0, h=0
    biasfrag.y = 0u; biasfrag.z = 0u; biasfrag.w = 0u;

    uint4 B[2][8];          // per-slot B-frags (z^T), packed bf16 dwords
    f32x16 sacc[4];
    #pragma unroll
    for (int nt = 0; nt < 4; nt++)
        #pragma unroll
        for (int r = 0; r < 16; r++) sacc[nt][r] = 0.f;

    for (int sc = 0; sc < 4; sc++) {
        int t0 = sc * 8 + wave * 2;
        for (int layer = 0; layer < 3; layer++) {
            __syncthreads();                    // prior readers done
            {   // stage this layer's weights: 2304 x 16B
                const uint4* src = (const uint4*)(wfrag + layer * 18432);
                #pragma unroll
                for (int it = 0; it < 9; it++) {
                    int idx = it * 256 + tid;
                    *(uint4*)&Wlds[idx * 8] = src[idx];
                }
            }
            __syncthreads();                    // weights visible

            #pragma unroll
            for (int slot = 0; slot < 2; slot++) {
                int t_loc = t0 + slot;
                if (t_loc >= 25) continue;
                int tileb = sub * 25 + t_loc;

                if (layer == 0) {
                    // build B[slot] = z0^T frags from vv/uu
                    int i  = (tileb / 10) * 2  + (lo >> 4);
                    int jj = (tileb % 10) * 16 + (lo & 15);
                    const float* vr = vv + ((size_t)(b * 160 + i))  * 128 + 8 * h;
                    const float* ur = uu + ((size_t)(b * 160 + jj)) * 128 + 8 * h;
                    #pragma unroll
                    for (int ks = 0; ks < 8; ks++) {
                        f32x4 v0 = *(const f32x4*)(vr + 16 * ks);
                        f32x4 v1 = *(const f32x4*)(vr + 16 * ks + 4);
                        f32x4 u0 = *(const f32x4*)(ur + 16 * ks);
                        f32x4 u1 = *(const f32x4*)(ur + 16 * ks + 4);
                        uint4 d;
                        d.x = pack_rn(lrelu(v0[0]+u0[0]), lrelu(v0[1]+u0[1]));
                        d.y = pack_rn(lrelu(v0[2]+u0[2]), lrelu(v0[3]+u0[3]));
                        d.z = pack_rn(lrelu(v1[0]+u1[0]), lrelu(v1[1]+u1[1]));
                        d.w = pack_rn(lrelu(v1[2]+u1[2]), lrelu(v1[3]+u1[3]));
                        B[slot][ks] = d;
                    }
                }

                // D[nt] = W x z^T  (+bias via 9th K-tile)
                f32x16 acc[4];
                #pragma unroll
                for (int nt = 0; nt < 4; nt++) {
                    f32x16 a;
                    #pragma unroll
                    for (int r = 0; r < 16; r++) a[r] = 0.f;
                    #pragma unroll
                    for (int ks = 0; ks < 9; ks++) {
                        bf16x8 af = *(const bf16x8*)&Wlds[(size_t)(ks * 256 + h * 128 + nt * 32 + lo) * 8];
                        uint4 bu = (ks < 8) ? B[slot][ks] : biasfrag;
                        bf16x8 bf = *(bf16x8*)&bu;
                        a = __builtin_amdgcn_mfma_f32_32x32x16_bf16(af, bf, a, 0, 0, 0);
                    }
                    acc[nt] = a;
                }

                if (layer < 2) {
                    // C-layout -> B-layout, in-register (all nt read before any write)
                    #pragma unroll
                    for (int nt = 0; nt < 4; nt++) {
                        u32 pk[4][2];
                        #pragma unroll
                        for (int c = 0; c < 4; c++)
                            #pragma unroll
                            for (int p = 0; p < 2; p++)
                                pk[c][p] = pack_rn(lrelu(acc[nt][c + 8*p]),
                                                   lrelu(acc[nt][c + 4 + 8*p]));
                        u32 sh[2][4][2];
                        #pragma unroll
                        for (int g = 0; g < 2; g++)
                            #pragma unroll
                            for (int c = 0; c < 4; c++)
                                #pragma unroll
                                for (int p = 0; p < 2; p++)
                                    sh[g][c][p] = (u32)__shfl((int)pk[c][p], g * 32 + lo, 64);
                        #pragma unroll
                        for (int p = 0; p < 2; p++) {
                            uint4 d;
                            d.x = __builtin_amdgcn_perm(sh[0][1][p], sh[0][0][p], selv);
                            d.y = __builtin_amdgcn_perm(sh[0][3][p], sh[0][2][p], selv);
                            d.z = __builtin_amdgcn_perm(sh[1][1][p], sh[1][0][p], selv);
                            d.w = __builtin_amdgcn_perm(sh[1][3][p], sh[1][2][p], selv);
                            B[slot][2 * nt + p] = d;
                        }
                    }
                } else {
                    #pragma unroll
                    for (int nt = 0; nt < 4; nt++)
                        #pragma unroll
                        for (int r = 0; r < 16; r++)
                            sacc[nt][r] += lrelu(acc[nt][r]);
                }
            }
        }
    }

    // reduce over m (lane&31) and flush
    #pragma unroll
    for (int nt = 0; nt < 4; nt++)
        #pragma unroll
        for (int r = 0; r < 16; r++) {
            float v = sacc[nt][r];
            v += __shfl_xor(v, 1);  v += __shfl_xor(v, 2);
            v += __shfl_xor(v, 4);  v += __shfl_xor(v, 8);
            v += __shfl_xor(v, 16);
            if (lo == 0) {
                int n = nt * 32 + (r & 3) + 8 * (r >> 2) + 4 * h;
                atomicAdd(&spart[n], v);
            }
        }
    __syncthreads();
    if (tid < 128) atomicAdd(&s_glob[b * 128 + tid], spart[tid]);
}

// ---------------------------------------------------------------------------
// Final: s -> lrelu(W5) -> lrelu(W6) -> out (unchanged).
// ---------------------------------------------------------------------------
__global__ __launch_bounds__(128) void k_final(
    const float* __restrict__ s_glob,
    const float* __restrict__ W5, const float* __restrict__ b5,
    const float* __restrict__ W6, const float* __restrict__ b6,
    float* __restrict__ out)
{
    __shared__ float sh[128], t5[128];
    int b = blockIdx.x, t = threadIdx.x;
    sh[t] = s_glob[b * 128 + t];
    __syncthreads();
    float acc = b5[t];
    const float* wr = W5 + (size_t)t * 128;
    for (int k = 0; k < 128; k++) acc += sh[k] * wr[k];
    t5[t] = lrelu(acc);
    __syncthreads();
    for (int q = 0; q < 4; q++) {
        int o = q * 128 + t;
        const float* w6r = W6 + (size_t)o * 128;
        float a2 = b6[o];
        for (int k = 0; k < 128; k++) a2 += t5[k] * w6r[k];
        out[b * 512 + o] = lrelu(a2);
    }
}

// ---------------------------------------------------------------------------
extern "C" void kernel_launch(void* const* d_in, const int* in_sizes, int n_in,
                              void* d_out, int out_size, void* d_ws, size_t ws_size,
                              hipStream_t stream)
{
    const float* x      = (const float*)d_in[0];
    const float* h      = (const float*)d_in[1];
    const float* conv_w = (const float*)d_in[2];
    const float* conv_b = (const float*)d_in[3];
    const float* bn_g   = (const float*)d_in[4];
    const float* bn_b   = (const float*)d_in[5];
    const float* W1     = (const float*)d_in[6];
    const float* b1     = (const float*)d_in[7];
    const float* W2     = (const float*)d_in[8];
    const float* b2     = (const float*)d_in[9];
    const float* W3     = (const float*)d_in[10];
    const float* b3     = (const float*)d_in[11];
    const float* W4     = (const float*)d_in[12];
    const float* b4     = (const float*)d_in[13];
    const float* W5     = (const float*)d_in[14];
    const float* b5     = (const float*)d_in[15];
    const float* W6     = (const float*)d_in[16];
    const float* b6     = (const float*)d_in[17];

    char* ws = (char*)d_ws;
    float* s_glob = (float*)(ws + 0);          //  8 KB
    float* stats  = (float*)(ws + 8192);       //  2 KB
    float* hW     = (float*)(ws + 10240);      //  8 KB
    float* ws_y   = (float*)(ws + 18432);      //  2.62 MB
    float* vv     = (float*)(ws + 2639872);    //  1.31 MB
    float* uu     = (float*)(ws + 3950592);    //  1.31 MB
    u16*   xb     = (u16*)  (ws + 5261312);    //  2.62 MB
    u16*   wcb    = (u16*)  (ws + 7882752);    //  786 KB
    u16*   wfrag  = (u16*)  (ws + 8669184);    //  110.6 KB (end 8,779,776)

    hipMemsetAsync(ws, 0, 10240, stream);      // zero s_glob + stats
    k_prep <<<1726, 256, 0, stream>>>(x, conv_w, W2, W3, W4, b2, b3, b4, h, W1,
                                      xb, wcb, wfrag, hW);
    k_conv <<<320, 256, 0, stream>>>(xb, wcb, conv_b, ws_y, stats);
    k_uv   <<<320, 256, 0, stream>>>(ws_y, stats, bn_g, bn_b, W1, b1, hW, uu, vv);
    k_mlp  <<<512, 256, 0, stream>>>(vv, uu, wfrag, s_glob);
    k_final<<<16, 128, 0, stream>>>(s_glob, W5, b5, W6, b6, (float*)d_out);
}